// Round 1
// baseline (432.758 us; speedup 1.0000x reference)
//
#include <hip/hip_runtime.h>
#include <hip/hip_bf16.h>

typedef short bf16x8 __attribute__((ext_vector_type(8)));
typedef float f32x4 __attribute__((ext_vector_type(4)));

#define NB 16384
#define IN_DIM 512
#define HD 1024
#define KTOT 1536
#define BM 128
#define NT 512
#define KIT (KTOT / 32)

__device__ __forceinline__ short f2b(float f) {
    __hip_bfloat16 h = __float2bfloat16(f);
    return *reinterpret_cast<short*>(&h);
}

__global__ __launch_bounds__(NT, 2) void slstm_fused(
    const float* __restrict__ x, const float* __restrict__ c_p,
    const float* __restrict__ h_p, const float* __restrict__ n_p,
    const float* __restrict__ m_p, const float* __restrict__ w_w,
    const float* __restrict__ w_b, const float* __restrict__ r_w,
    const float* __restrict__ r_b, float* __restrict__ out)
{
    // LDS tiles, padded to 40 shorts/row (80B) for uniform bank spread on b128
    __shared__ __align__(16) short As[BM * 40];   // [128 rows][32 k]
    __shared__ __align__(16) short Bs[256 * 40];  // [256 cols][32 k], col-major by k

    const int t    = threadIdx.x;
    const int lane = t & 63;
    const int wid  = t >> 6;
    const int wm   = wid >> 2;   // 0..1 : M half
    const int wn   = wid & 3;    // 0..3 : 16-h-col group
    const int l15  = lane & 15;
    const int l4   = lane >> 4;

    const int bm = (int)blockIdx.x >> 4;   // 0..127
    const int bh = (int)blockIdx.x & 15;   // 0..15
    const int m0 = bm * BM;
    const int h0 = bh * 64;

    // A staging: thread covers row t>>2, k-cols [(t&3)*8, +8)
    const int a_row = t >> 2;
    const int a_c   = (t & 3) << 3;

    // B staging: 2 assignments/thread; cid in [0,256) = wn*64 + g*16 + c15
    // mapping cid -> gate g = (cid>>4)&3, h-col jh = (cid>>6)*16 + (cid&15)
    int b_cid[2], b_kc[2], b_gcol[2];
#pragma unroll
    for (int a = 0; a < 2; ++a) {
        int idx  = t + a * NT;
        b_cid[a] = idx & 255;
        b_kc[a]  = (idx >> 8) << 3;          // 0,8,16,24
        int g    = (b_cid[a] >> 4) & 3;
        int jh   = ((b_cid[a] >> 6) << 4) | (b_cid[a] & 15);
        b_gcol[a] = g * HD + h0 + jh;
    }

    f32x4 acc[4][4];  // [m-frag][gate]
    const f32x4 zero = {0.f, 0.f, 0.f, 0.f};
#pragma unroll
    for (int i = 0; i < 4; ++i)
#pragma unroll
        for (int j = 0; j < 4; ++j) acc[i][j] = zero;

    for (int kt = 0; kt < KIT; ++kt) {
        const int k0 = kt << 5;

        // ---- global loads into registers (overlap previous compute) ----
        float4 av0, av1;
        {
            const float* ap = (k0 < IN_DIM)
                ? x   + (size_t)(m0 + a_row) * IN_DIM + (k0 + a_c)
                : h_p + (size_t)(m0 + a_row) * HD     + (k0 - IN_DIM + a_c);
            av0 = *(const float4*)ap;
            av1 = *(const float4*)(ap + 4);
        }
        float bv[2][8];
#pragma unroll
        for (int a = 0; a < 2; ++a) {
            const float* bp = ((k0 < IN_DIM)
                ? w_w + (size_t)(k0 + b_kc[a]) * 4096
                : r_w + (size_t)(k0 - IN_DIM + b_kc[a]) * 4096) + b_gcol[a];
#pragma unroll
            for (int kk = 0; kk < 8; ++kk) bv[a][kk] = bp[(size_t)kk * 4096];
        }

        __syncthreads();  // previous iteration's LDS reads complete

        // ---- convert + LDS write ----
        {
            bf16x8 v;
            v[0] = f2b(av0.x); v[1] = f2b(av0.y); v[2] = f2b(av0.z); v[3] = f2b(av0.w);
            v[4] = f2b(av1.x); v[5] = f2b(av1.y); v[6] = f2b(av1.z); v[7] = f2b(av1.w);
            *(bf16x8*)&As[a_row * 40 + a_c] = v;
        }
#pragma unroll
        for (int a = 0; a < 2; ++a) {
            bf16x8 v;
#pragma unroll
            for (int kk = 0; kk < 8; ++kk) v[kk] = f2b(bv[a][kk]);
            *(bf16x8*)&Bs[b_cid[a] * 40 + b_kc[a]] = v;
        }

        __syncthreads();

        // ---- fragments + MFMA ----
        bf16x8 af[4], bfr[4];
#pragma unroll
        for (int mi = 0; mi < 4; ++mi)
            af[mi] = *(const bf16x8*)&As[(wm * 64 + mi * 16 + l15) * 40 + (l4 << 3)];
#pragma unroll
        for (int g = 0; g < 4; ++g)
            bfr[g] = *(const bf16x8*)&Bs[(wn * 64 + g * 16 + l15) * 40 + (l4 << 3)];
#pragma unroll
        for (int mi = 0; mi < 4; ++mi)
#pragma unroll
            for (int g = 0; g < 4; ++g)
                acc[mi][g] = __builtin_amdgcn_mfma_f32_16x16x32_bf16(
                    af[mi], bfr[g], acc[mi][g], 0, 0, 0);
    }

    // ---- fused epilogue: all 4 gates of (row, h) are lane-local ----
    const int h = h0 + wn * 16 + l15;
    float bias[4];
#pragma unroll
    for (int g = 0; g < 4; ++g) bias[g] = w_b[g * HD + h] + r_b[g * HD + h];

    const size_t PL = (size_t)NB * HD;
#pragma unroll
    for (int mi = 0; mi < 4; ++mi) {
#pragma unroll
        for (int r = 0; r < 4; ++r) {
            const int row = m0 + wm * 64 + mi * 16 + l4 * 4 + r;
            const size_t idx = (size_t)row * HD + h;
            const float ci = acc[mi][0][r] + bias[0];
            const float ig = acc[mi][1][r] + bias[1];
            const float fg = acc[mi][2][r] + bias[2];
            const float og = acc[mi][3][r] + bias[3];
            const float mp  = m_p[idx];
            const float cp  = c_p[idx];
            const float np_ = n_p[idx];
            const float z  = tanhf(ci);
            const float it = expf(ig);
            const float mt = fmaxf(fg + mp, ig);
            const float sf = expf(fg + mp - mt);
            const float si = expf(ig - mt);
            const float ct = sf * cp + it * z;
            const float nt = sf * np_ + si;
            const float ot = 1.0f / (1.0f + expf(-og));
            const float ht = ot * (ct / nt);
            out[idx]          = ht;
            out[PL + idx]     = ct;
            out[2 * PL + idx] = ht;
            out[3 * PL + idx] = nt;
            out[4 * PL + idx] = mt;
        }
    }
}

extern "C" void kernel_launch(void* const* d_in, const int* in_sizes, int n_in,
                              void* d_out, int out_size, void* d_ws, size_t ws_size,
                              hipStream_t stream) {
    const float* x   = (const float*)d_in[0];
    const float* c_p = (const float*)d_in[1];
    const float* h_p = (const float*)d_in[2];
    const float* n_p = (const float*)d_in[3];
    const float* m_p = (const float*)d_in[4];
    const float* w_w = (const float*)d_in[5];
    const float* w_b = (const float*)d_in[6];
    const float* r_w = (const float*)d_in[7];
    const float* r_b = (const float*)d_in[8];
    float* out = (float*)d_out;

    dim3 grid(128 * 16);  // (16384/128) M-blocks x (1024/64) h-blocks
    slstm_fused<<<grid, NT, 0, stream>>>(x, c_p, h_p, n_p, m_p, w_w, w_b, r_w, r_b, out);
}

// Round 2
// 342.203 us; speedup vs baseline: 1.2646x; 1.2646x over previous
//
#include <hip/hip_runtime.h>
#include <hip/hip_bf16.h>

typedef short bf16x8 __attribute__((ext_vector_type(8)));
typedef float f32x4 __attribute__((ext_vector_type(4)));

#define NB 16384
#define IN_DIM 512
#define HD 1024
#define NT 512
#define KTILES 48

__device__ __forceinline__ short f2b(float f) {
    __hip_bfloat16 h = __float2bfloat16(f);
    return *reinterpret_cast<short*>(&h);
}

__device__ __forceinline__ void gload16(const void* g, void* l) {
    __builtin_amdgcn_global_load_lds(
        (const __attribute__((address_space(1))) void*)g,
        (__attribute__((address_space(3))) void*)l, 16, 0, 0);
}

// ---------------- prepass: weights -> bf16 swizzled tiles ----------------
// wsB tiles: [bh 0..15][kt 0..47] each 256 cols x 32 k bf16 (16 KB), row=64B,
// element (cid,k) at byte cid*64 + ((k*2) ^ (((cid>>1)&3)<<4))
__global__ void prep_w(const float* __restrict__ w_w, const float* __restrict__ r_w,
                       short* __restrict__ wsB) {
    const int blk = blockIdx.x;          // bh*48 + kt
    const int kt  = blk % KTILES;
    const int cid = threadIdx.x;         // 0..255
    const int bh  = blk / KTILES;
    const int g   = (cid >> 4) & 3;
    const int jh  = ((cid >> 6) << 4) | (cid & 15);
    const int gcol = g * HD + bh * 64 + jh;

    const float* src = (kt < 16) ? w_w : r_w;
    const int kbase  = (kt < 16) ? kt * 32 : (kt - 16) * 32;

    float v[32];
#pragma unroll
    for (int kk = 0; kk < 32; ++kk)
        v[kk] = src[(size_t)(kbase + kk) * 4096 + gcol];

    char* tile = (char*)(wsB + (size_t)blk * 8192);
    const int swz = ((cid >> 1) & 3) << 4;
#pragma unroll
    for (int s = 0; s < 4; ++s) {
        bf16x8 o;
#pragma unroll
        for (int j = 0; j < 8; ++j) o[j] = f2b(v[s * 8 + j]);
        *(bf16x8*)(tile + cid * 64 + ((s * 16) ^ swz)) = o;
    }
}

// ---------------- prepass: activations -> bf16 swizzled tiles ----------------
// wsA tiles: [bm 0..127][kt 0..47] each 128 rows x 32 k bf16 (8 KB)
__global__ void prep_a(const float* __restrict__ x, const float* __restrict__ h_p,
                       short* __restrict__ wsA) {
    const int blk  = blockIdx.x;         // bm*48 + kt
    const int kt   = blk % KTILES;
    const int bm   = blk / KTILES;
    const int t    = threadIdx.x;        // 0..255
    const int row  = t >> 1;
    const int half = t & 1;
    const int grow = bm * 128 + row;

    const float* src = (kt < 16)
        ? x   + (size_t)grow * IN_DIM + kt * 32 + half * 16
        : h_p + (size_t)grow * HD     + (kt - 16) * 32 + half * 16;

    float4 a0 = ((const float4*)src)[0];
    float4 a1 = ((const float4*)src)[1];
    float4 a2 = ((const float4*)src)[2];
    float4 a3 = ((const float4*)src)[3];
    float v[16] = {a0.x,a0.y,a0.z,a0.w, a1.x,a1.y,a1.z,a1.w,
                   a2.x,a2.y,a2.z,a2.w, a3.x,a3.y,a3.z,a3.w};

    char* tile = (char*)(wsA + (size_t)blk * 4096);
    const int swz = ((row >> 1) & 3) << 4;
#pragma unroll
    for (int s = 0; s < 2; ++s) {
        bf16x8 o;
#pragma unroll
        for (int j = 0; j < 8; ++j) o[j] = f2b(v[s * 8 + j]);
        *(bf16x8*)(tile + row * 64 + ((half * 32 + s * 16) ^ swz)) = o;
    }
}

// ---------------- main fused GEMM + epilogue ----------------
__global__ __launch_bounds__(NT, 4) void slstm_fused(
    const short* __restrict__ wsA, const short* __restrict__ wsB,
    const float* __restrict__ c_p, const float* __restrict__ n_p,
    const float* __restrict__ m_p, const float* __restrict__ w_b,
    const float* __restrict__ r_b, float* __restrict__ out)
{
    __shared__ __align__(16) short As[2][4096];   // 128 rows x 32 k, 64B rows
    __shared__ __align__(16) short Bs[2][8192];   // 256 cols x 32 k

    const int t    = threadIdx.x;
    const int lane = t & 63;
    const int wid  = t >> 6;
    const int wm   = wid >> 2;    // 0..1
    const int wn   = wid & 3;     // 0..3
    const int l15  = lane & 15;
    const int l4   = lane >> 4;

    const int bm = (int)blockIdx.x >> 4;
    const int bh = (int)blockIdx.x & 15;
    const int m0 = bm * 128;
    const int h0 = bh * 64;

    const short* atile = wsA + (size_t)(bm * KTILES) * 4096 + wid * 512 + lane * 8;
    const short* btile = wsB + (size_t)(bh * KTILES) * 8192 + wid * 1024 + lane * 8;

    f32x4 acc[4][4];
    const f32x4 zero = {0.f, 0.f, 0.f, 0.f};
#pragma unroll
    for (int i = 0; i < 4; ++i)
#pragma unroll
        for (int j = 0; j < 4; ++j) acc[i][j] = zero;

    // precompute swizzled fragment short-indices
    int aidx[4], bidx[4];
#pragma unroll
    for (int mi = 0; mi < 4; ++mi) {
        int row = wm * 64 + mi * 16 + l15;
        aidx[mi] = (row * 64 + ((l4 << 4) ^ (((row >> 1) & 3) << 4))) >> 1;
    }
#pragma unroll
    for (int g = 0; g < 4; ++g) {
        int col = wn * 64 + g * 16 + l15;
        bidx[g] = (col * 64 + ((l4 << 4) ^ (((col >> 1) & 3) << 4))) >> 1;
    }

    // prologue: stage kt=0 into buf 0
    gload16(atile, &As[0][wid * 512]);
    gload16(btile, &Bs[0][wid * 1024]);
    gload16(btile + 512, &Bs[0][wid * 1024 + 512]);
    __syncthreads();

    int p = 0;
    for (int kt = 0; kt < KTILES; ++kt) {
        if (kt < KTILES - 1) {
            const short* an = atile + (size_t)(kt + 1) * 4096;
            const short* bn = btile + (size_t)(kt + 1) * 8192;
            gload16(an, &As[p ^ 1][wid * 512]);
            gload16(bn, &Bs[p ^ 1][wid * 1024]);
            gload16(bn + 512, &Bs[p ^ 1][wid * 1024 + 512]);
        }

        bf16x8 af[4], bfr[4];
#pragma unroll
        for (int mi = 0; mi < 4; ++mi) af[mi]  = *(const bf16x8*)&As[p][aidx[mi]];
#pragma unroll
        for (int g = 0; g < 4; ++g)    bfr[g]  = *(const bf16x8*)&Bs[p][bidx[g]];
#pragma unroll
        for (int mi = 0; mi < 4; ++mi)
#pragma unroll
            for (int g = 0; g < 4; ++g)
                acc[mi][g] = __builtin_amdgcn_mfma_f32_16x16x32_bf16(
                    af[mi], bfr[g], acc[mi][g], 0, 0, 0);

        __syncthreads();   // drains vmcnt(0): next buf staged; buf p free
        p ^= 1;
    }

    // ---- fused epilogue: all 4 gates of (row,h) are lane-local ----
    const int h = h0 + wn * 16 + l15;
    float bias[4];
#pragma unroll
    for (int g = 0; g < 4; ++g) bias[g] = w_b[g * HD + h] + r_b[g * HD + h];

    const size_t PL = (size_t)NB * HD;
#pragma unroll
    for (int mi = 0; mi < 4; ++mi) {
#pragma unroll
        for (int r = 0; r < 4; ++r) {
            const int row = m0 + wm * 64 + mi * 16 + l4 * 4 + r;
            const size_t idx = (size_t)row * HD + h;
            const float ci = acc[mi][0][r] + bias[0];
            const float ig = acc[mi][1][r] + bias[1];
            const float fg = acc[mi][2][r] + bias[2];
            const float og = acc[mi][3][r] + bias[3];
            const float mp  = m_p[idx];
            const float cp  = c_p[idx];
            const float np_ = n_p[idx];
            const float z  = tanhf(ci);
            const float it = expf(ig);
            const float mt = fmaxf(fg + mp, ig);
            const float sf = expf(fg + mp - mt);
            const float si = expf(ig - mt);
            const float ct = sf * cp + it * z;
            const float nt = sf * np_ + si;
            const float ot = 1.0f / (1.0f + expf(-og));
            const float ht = ot * (ct / nt);
            out[idx]          = ht;
            out[PL + idx]     = ct;
            out[2 * PL + idx] = ht;
            out[3 * PL + idx] = nt;
            out[4 * PL + idx] = mt;
        }
    }
}

extern "C" void kernel_launch(void* const* d_in, const int* in_sizes, int n_in,
                              void* d_out, int out_size, void* d_ws, size_t ws_size,
                              hipStream_t stream) {
    const float* x   = (const float*)d_in[0];
    const float* c_p = (const float*)d_in[1];
    const float* h_p = (const float*)d_in[2];
    const float* n_p = (const float*)d_in[3];
    const float* m_p = (const float*)d_in[4];
    const float* w_w = (const float*)d_in[5];
    const float* w_b = (const float*)d_in[6];
    const float* r_w = (const float*)d_in[7];
    const float* r_b = (const float*)d_in[8];
    float* out = (float*)d_out;

    short* wsB = (short*)d_ws;                         // 16*48*16KB = 12.58 MB
    short* wsA = (short*)((char*)d_ws + (size_t)16 * KTILES * 16384);  // 50.33 MB

    prep_w<<<dim3(16 * KTILES), 256, 0, stream>>>(w_w, r_w, wsB);
    prep_a<<<dim3(128 * KTILES), 256, 0, stream>>>(x, h_p, wsA);
    slstm_fused<<<dim3(2048), NT, 0, stream>>>(wsA, wsB, c_p, n_p, m_p, w_b, r_b, out);
}